// Round 7
// baseline (369.256 us; speedup 1.0000x reference)
//
#include <hip/hip_runtime.h>
#include <hip/hip_bf16.h>
#include <cstdint>

// Problem shape (Transducer joint network):
//   enc (4,160,640) fp32, dec (4,80,640) fp32, W1 (1280,640), b1 (640),
//   W2 (640,1024), b2 (1024).  out = (4,160,80,1024) fp32 = 52.4M floats.
#define D_    640
#define V_    1024
#define M_    51200

typedef __bf16 bf16x8 __attribute__((ext_vector_type(8)));
typedef float floatx4 __attribute__((ext_vector_type(4)));

__device__ __forceinline__ void g2l16(const void* g, void* l) {
    __builtin_amdgcn_global_load_lds((const __attribute__((address_space(1))) void*)g,
                                     (__attribute__((address_space(3))) void*)l,
                                     16, 0, 0);
}

__device__ __forceinline__ float fast_tanh(float x) {
    float e = __builtin_amdgcn_exp2f(x * 2.8853900817779268f); // 2*log2(e)
    return 1.0f - 2.0f * __builtin_amdgcn_rcpf(e + 1.0f);
}

// ---------------------------------------------------------------------------
// Kernel 1: fp32 projections -> d_ws. 64x64 tiles, 4x4/thread.
// b1 FOLDED into encp (k-only bias): hidden = tanh((e+b1) + d).
// ---------------------------------------------------------------------------
__global__ __launch_bounds__(256) void proj_kernel(
    const float* __restrict__ enc, const float* __restrict__ dec,
    const float* __restrict__ W1, const float* __restrict__ b1,
    float* __restrict__ encp, float* __restrict__ decp) {
    __shared__ float As[64][36];
    __shared__ float Ws[32][68];

    const int rt = blockIdx.y;     // 0..14 (10 enc row-tiles, 5 dec row-tiles)
    const int ct = blockIdx.x;     // 0..9
    const bool is_enc = (rt < 10);
    const float* Asrc; const float* Wsrc; float* Cdst;
    if (is_enc) { Asrc = enc + (size_t)rt * 64 * D_;        Wsrc = W1;           Cdst = encp + (size_t)rt * 64 * D_; }
    else        { Asrc = dec + (size_t)(rt - 10) * 64 * D_; Wsrc = W1 + D_ * D_; Cdst = decp + (size_t)(rt - 10) * 64 * D_; }

    const int tid = threadIdx.x;
    const int ar = tid >> 2,  ac = (tid & 3) * 8;
    const int wr2 = tid >> 3, wc2 = (tid & 7) * 8;
    const int tr = tid >> 4,  tc = tid & 15;

    float acc[4][4] = {};
    for (int k0 = 0; k0 < D_; k0 += 32) {
        __syncthreads();
        *(floatx4*)&As[ar][ac]       = *(const floatx4*)&Asrc[(size_t)ar * D_ + k0 + ac];
        *(floatx4*)&As[ar][ac + 4]   = *(const floatx4*)&Asrc[(size_t)ar * D_ + k0 + ac + 4];
        *(floatx4*)&Ws[wr2][wc2]     = *(const floatx4*)&Wsrc[(size_t)(k0 + wr2) * D_ + ct * 64 + wc2];
        *(floatx4*)&Ws[wr2][wc2 + 4] = *(const floatx4*)&Wsrc[(size_t)(k0 + wr2) * D_ + ct * 64 + wc2 + 4];
        __syncthreads();
#pragma unroll
        for (int kk = 0; kk < 32; kk++) {
            floatx4 w = *(const floatx4*)&Ws[kk][tc * 4];
            float a0 = As[tr * 4 + 0][kk], a1 = As[tr * 4 + 1][kk];
            float a2 = As[tr * 4 + 2][kk], a3 = As[tr * 4 + 3][kk];
#pragma unroll
            for (int j = 0; j < 4; j++) {
                acc[0][j] += a0 * w[j]; acc[1][j] += a1 * w[j];
                acc[2][j] += a2 * w[j]; acc[3][j] += a3 * w[j];
            }
        }
    }
    floatx4 bv = {0.f, 0.f, 0.f, 0.f};
    if (is_enc) bv = *(const floatx4*)&b1[ct * 64 + tc * 4];
#pragma unroll
    for (int i = 0; i < 4; i++) {
        floatx4 v = { acc[i][0] + bv[0], acc[i][1] + bv[1],
                      acc[i][2] + bv[2], acc[i][3] + bv[3] };
        *(floatx4*)&Cdst[(size_t)(tr * 4 + i) * D_ + ct * 64 + tc * 4] = v;
    }
}

// ---------------------------------------------------------------------------
// Kernel 2: W2 (640x1024 fp32 KxN) -> W2t (1024x640 bf16 NxK) in d_ws.
// ---------------------------------------------------------------------------
__global__ __launch_bounds__(256) void w2t_kernel(
    const float* __restrict__ W2, __bf16* __restrict__ W2t) {
    __shared__ __bf16 tile[32][33];
    const int vt = blockIdx.x;           // 0..31
    const int kt = blockIdx.y;           // 0..19
    const int tx = threadIdx.x & 31, ty = threadIdx.x >> 5;
#pragma unroll
    for (int i = 0; i < 4; i++)
        tile[ty + i * 8][tx] = (__bf16)W2[(size_t)(kt * 32 + ty + i * 8) * V_ + vt * 32 + tx];
    __syncthreads();
#pragma unroll
    for (int i = 0; i < 4; i++)
        W2t[(size_t)(vt * 32 + ty + i * 8) * D_ + kt * 32 + tx] = tile[tx][ty + i * 8];
}

// ---------------------------------------------------------------------------
// Kernel 3 (fused): C = tanh(encp'[bt] + decp[drw]) @ W2t^T + b2.
//
// ROUND-7 GEOMETRY CHANGE. r6 PMC decomposition per CU (338k cyc): MFMA 78k
// (23%) + LDS 94k (28%) + VALU 125k (37%) -> pipes SUM, and MFMA was the
// SMALLEST pole, so no schedule could win. Fix: raise MFMA per phase.
//   BM=128, BN=256, BK=64, 256 thr = 4 waves, per-wave out 128x64
//   (acc[8][4]; frag reuse 8x4 -> 0.375 KB LDS per MFMA vs r6's 0.5).
//   A SINGLE-buffered 16KB (produced per K-tile), B double 2x32KB ->
//   80KB LDS, 2 blocks/CU. 1600 blocks (400 mt x 4 nt).
// Per block-tile: MFMA 1242 cyc (2x r6) >> LDS ~660 >> produce ~500:
// MFMA is now the long pole; partner block hides phase2.
// Two __syncthreads per tile carry all hazards (A WAR: read P1/write P2;
// B[nb] last read 2 barriers before restage; g2l drained by P2 barrier).
// No inline-asm waits, no SCB (r5 vs r6: compiler scheduling was better).
// Same conflict-free involution slot16 ^= (row&7) on all LDS paths.
// ---------------------------------------------------------------------------
__global__ __launch_bounds__(256, 2) void joint_kernel(
    const float* __restrict__ encp, const float* __restrict__ decp,
    const __bf16* __restrict__ W2t, const float* __restrict__ b2,
    float* __restrict__ C) {
    __shared__ __align__(128) char lds[81920];   // A: 16KB @0, B: 2x32KB @16384

    const int bid = blockIdx.x;
    const int swz = (bid & 7) * 200 + (bid >> 3);   // 1600 = 8 XCD x 200
    const int mt = swz >> 2, nt = swz & 3;          // 400 M-tiles x 4 N-tiles
    const int m0 = mt * 128, n0 = nt * 256;

    const int tid = threadIdx.x;                    // 0..255
    const int w = tid >> 6, l = tid & 63;           // 4 waves; wave = N-col w
    const int lr = l & 15, lk = l >> 4;

    char* ldsp = (char*)lds;

    // ---- B staging: 8 g2l16/thread/tile; source column pre-swizzled so
    // linear LDS dest yields lds[row][slot] = W2t[row][slot ^ (row&7)].
    const char* Wb = (const char*)W2t
        + (size_t)(n0 + (tid >> 3)) * 1280
        + (unsigned)((((tid & 7) ^ ((tid >> 3) & 7)) * 16));
    const unsigned bdst = 16384u + (unsigned)tid * 16u;

    // ---- A produce: thread owns row pr (0..127), k-half kh (32 elems).
    const int pr = tid >> 1;
    const int kh = (tid & 1) * 32;
    const int R  = m0 + pr;
    const int bt = R / 80;
    const int uu = R - bt * 80;
    const int drw = (bt / 160) * 80 + uu;
    const float* ep = encp + (size_t)bt * D_ + kh;   // b1 already folded in
    const float* dp = decp + (size_t)drw * D_ + kh;
    // write slots: sub-batch sub in {0,1} covers elems kh+sub*16..+16
    // -> logical slots s0=(tid&1)*4+sub*2, s0+1 ; phys = slot ^ (pr&7)
    const unsigned prb = (unsigned)(pr * 128);
    const unsigned ps0 = (unsigned)((tid & 1) * 4);
    const unsigned px  = (unsigned)(pr & 7);

    floatx4 acc[8][4] = {};

#define STAGE_B(BUF, T) do { \
    const char* _s = Wb + (size_t)(T) * 128; \
    char* _d = ldsp + bdst + (BUF) * 32768; \
    g2l16(_s,           _d); \
    g2l16(_s +  40960,  _d +  4096); \
    g2l16(_s +  81920,  _d +  8192); \
    g2l16(_s + 122880,  _d + 12288); \
    g2l16(_s + 163840,  _d + 16384); \
    g2l16(_s + 204800,  _d + 20480); \
    g2l16(_s + 245760,  _d + 24576); \
    g2l16(_s + 286720,  _d + 28672); \
  } while (0)

// produce 32 H-elems for tile T into the single A buffer (2 sub-batches
// of 16 elems each to cap live VGPRs at ~32 per batch).
#define PRODUCE_A(T) do { \
    _Pragma("unroll") for (int sub = 0; sub < 2; ++sub) { \
      const float* _e = ep + (T) * 64 + sub * 16; \
      const float* _d = dp + (T) * 64 + sub * 16; \
      floatx4 ev[4], dv[4]; \
      _Pragma("unroll") for (int q = 0; q < 4; ++q) { \
        ev[q] = *(const floatx4*)(_e + q * 4); \
        dv[q] = *(const floatx4*)(_d + q * 4); \
      } \
      bf16x8 h0, h1; \
      _Pragma("unroll") for (int q = 0; q < 4; ++q) { \
        _Pragma("unroll") for (int i2 = 0; i2 < 4; ++i2) { \
          float t_ = fast_tanh(ev[q][i2] + dv[q][i2]); \
          if (q < 2) h0[q * 4 + i2] = (__bf16)t_; else h1[(q - 2) * 4 + i2] = (__bf16)t_; \
        } } \
      *(bf16x8*)(ldsp + prb + (((ps0 + sub * 2)     ^ px) * 16)) = h0; \
      *(bf16x8*)(ldsp + prb + (((ps0 + sub * 2 + 1) ^ px) * 16)) = h1; \
    } } while (0)

#define FRAGS_MFMA(BUF) do { \
    _Pragma("unroll") \
    for (int s = 0; s < 2; ++s) { \
        const unsigned sx = (unsigned)((((s * 4 + lk) ^ (lr & 7)) * 16)); \
        bf16x8 af[8], bfr[4]; \
        _Pragma("unroll") for (int i = 0; i < 8; ++i) \
            af[i] = *(const bf16x8*)(ldsp + (i * 16 + lr) * 128 + sx); \
        _Pragma("unroll") for (int j = 0; j < 4; ++j) \
            bfr[j] = *(const bf16x8*)(ldsp + 16384 + (BUF) * 32768 + (w * 64 + j * 16 + lr) * 128 + sx); \
        _Pragma("unroll") for (int i = 0; i < 8; ++i) \
            _Pragma("unroll") for (int j = 0; j < 4; ++j) \
                acc[i][j] = __builtin_amdgcn_mfma_f32_16x16x32_bf16(af[i], bfr[j], acc[i][j], 0, 0, 0); \
    } } while (0)

    // ---- prologue: stage B(0), produce A(0) ----
    STAGE_B(0, 0);
    PRODUCE_A(0);
    __syncthreads();                       // drains g2l + ds_writes

#pragma unroll 1
    for (int t = 0; t < 9; ++t) {
        const int buf = t & 1, nb = buf ^ 1;
        FRAGS_MFMA(buf);                   // phase1: reads A + B[buf], MFMA
        __syncthreads();                   // all reads done before A rewrite
        STAGE_B(nb, t + 1);                // phase2: next B + next A
        PRODUCE_A(t + 1);
        __syncthreads();                   // stage+produce visible
    }
    FRAGS_MFMA(1);                         // t = 9 (buf=1), compute only

    // ---- epilogue: C/D layout col = lane&15 (N), row = (lane>>4)*4+reg (M) ----
#pragma unroll
    for (int j = 0; j < 4; ++j) {
        const int col = n0 + w * 64 + j * 16 + lr;
        const float bj = b2[col];
#pragma unroll
        for (int i = 0; i < 8; ++i) {
            const int row = m0 + i * 16 + lk * 4;
            float* Cp = C + (size_t)row * V_ + col;
#pragma unroll
            for (int rg = 0; rg < 4; ++rg)
                Cp[(size_t)rg * V_] = acc[i][j][rg] + bj;
        }
    }
#undef STAGE_B
#undef PRODUCE_A
#undef FRAGS_MFMA
}

// ---------------------------------------------------------------------------
extern "C" void kernel_launch(void* const* d_in, const int* in_sizes, int n_in,
                              void* d_out, int out_size, void* d_ws, size_t ws_size,
                              hipStream_t stream) {
    const float* enc = (const float*)d_in[0];
    const float* dec = (const float*)d_in[1];
    const float* W1  = (const float*)d_in[2];
    const float* b1  = (const float*)d_in[3];
    const float* W2  = (const float*)d_in[4];
    const float* b2  = (const float*)d_in[5];
    float* out = (float*)d_out;

    // Workspace (d_ws):
    char* ws = (char*)d_ws;
    float*  encp = (float*)ws;                         // 640*640*4  = 1,638,400 (b1 folded)
    float*  decp = (float*)(ws + 1638400);             // 320*640*4  =   819,200
    __bf16* W2t  = (__bf16*)(ws + 1638400 + 819200);   // 1024*640*2 = 1,310,720

    proj_kernel<<<dim3(10, 15), 256, 0, stream>>>(enc, dec, W1, b1, encp, decp);
    w2t_kernel<<<dim3(32, 20), 256, 0, stream>>>(W2, W2t);
    joint_kernel<<<1600, 256, 0, stream>>>(encp, decp, W2t, b2, out);
}